// Round 18
// baseline (1465.697 us; speedup 1.0000x reference)
//
#include <hip/hip_runtime.h>
#include <stdint.h>

typedef unsigned int uint;
typedef unsigned short ushort;
typedef __attribute__((ext_vector_type(4))) float f32x4;
typedef __attribute__((ext_vector_type(8))) short short8;
typedef __attribute__((ext_vector_type(2))) uint uint2v;
typedef __attribute__((ext_vector_type(4))) uint uint4v;

#define GLOBAL_AS __attribute__((address_space(1)))
#define LDS_AS __attribute__((address_space(3)))

static constexpr int B_ = 2048, IN_ = 4096, OUT_ = 4096;
static constexpr int NT = 32;   // K chunks of 128 (crossbar tiles)
static constexpr int K = IN_;
static constexpr int NKT = 64;  // K-tiles of BK=64
static constexpr int MAXB = 256;   // maxabs partial blocks (fused into k_prep)
static constexpr int NSLOT = 8;    // per-chunk max/arrival slots
static constexpr uint NARRIVE = 64;  // 512 blocks / 8 slots

static constexpr double kGRangeD = 1e-4 - 1e-5;
static constexpr float kGMin  = 1e-5f;
static constexpr float kGMax  = 1e-4f;
static constexpr float kGRange = (float)kGRangeD;            // 9e-5
static constexpr float kD2D   = (float)(0.01 * kGRangeD);    // D2D_STD
static constexpr float kRead  = (float)(0.02 * kGRangeD);    // READ_NOISE_STD
static constexpr float kInvGR = (float)(1.0 / kGRangeD);     // decode scale

// scal layout (uints): [0]=max|x|; [8..264)=maxslot[32][8]; [264..520)=cnt[32][8]

// ---------------- fused: maxabs partials (blocks < MAXB) + weff ------------
__global__ __launch_bounds__(256) void k_prep(const f32x4* __restrict__ x, int n4,
                                              float* __restrict__ part,
                                              const f32x4* __restrict__ W,
                                              const f32x4* __restrict__ dp,
                                              const f32x4* __restrict__ dn,
                                              const f32x4* __restrict__ npz,
                                              const f32x4* __restrict__ nnz,
                                              uint2v* __restrict__ wb) {
    const int bid = blockIdx.x;
    const int tid = threadIdx.x;

    if (bid < MAXB) {
        __shared__ float wmax[4];
        int stride = MAXB * 256;
        float m = 0.f;
        for (int i = bid * 256 + tid; i < n4; i += stride) {
            f32x4 v = x[i];
            m = fmaxf(m, fmaxf(fmaxf(fabsf(v[0]), fabsf(v[1])),
                               fmaxf(fabsf(v[2]), fabsf(v[3]))));
        }
#pragma unroll
        for (int off = 32; off; off >>= 1) m = fmaxf(m, __shfl_xor(m, off, 64));
        if ((tid & 63) == 0) wmax[tid >> 6] = m;
        __syncthreads();
        if (tid == 0)
            part[bid] = fmaxf(fmaxf(wmax[0], wmax[1]), fmaxf(wmax[2], wmax[3]));
        return;
    }

    // ---- weff: one-shot 16 elems/thread, NT loads ----
    const int wid = ((bid - MAXB) * 256 + tid) >> 6;  // global wave id
    const int lane = tid & 63;
    const size_t base = (size_t)wid * 256 + lane;     // f32x4 index; +64 per j

    f32x4 w[4], a[4], b[4], c[4], d[4];
#pragma unroll
    for (int j = 0; j < 4; ++j) {
        w[j] = __builtin_nontemporal_load(&W[base + j * 64]);
        a[j] = __builtin_nontemporal_load(&dp[base + j * 64]);
        b[j] = __builtin_nontemporal_load(&dn[base + j * 64]);
        c[j] = __builtin_nontemporal_load(&npz[base + j * 64]);
        d[j] = __builtin_nontemporal_load(&nnz[base + j * 64]);
    }
#pragma unroll
    for (int j = 0; j < 4; ++j) {
        uint h[4];
#pragma unroll
        for (int e = 0; e < 4; ++e) {
            float wc = fminf(fmaxf(w[j][e], -1.f), 1.f);
            float gp = kGMin + fmaxf(wc, 0.f) * kGRange;
            float gn = kGMin + fmaxf(-wc, 0.f) * kGRange;
            gp = fminf(fmaxf(gp + kD2D * a[j][e] + kRead * c[j][e], 0.f), kGMax);
            gn = fminf(fmaxf(gn + kD2D * b[j][e] + kRead * d[j][e], 0.f), kGMax);
            float wv = (gp - gn) * kInvGR;
            uint u = __float_as_uint(wv);
            h[e] = (u + 0x7FFFu + ((u >> 16) & 1u)) >> 16;  // RNE to bf16
        }
        uint2v o;
        o[0] = h[0] | (h[1] << 16); o[1] = h[2] | (h[3] << 16);
        wb[base + j * 64] = o;
    }
}

// ---------------- DAC quantize x (+ partial-max reduce + slot zeroing) ----
__global__ __launch_bounds__(256) void k_quantx(const f32x4* __restrict__ x,
                                                uint4v* __restrict__ xq, int n8,
                                                const float* __restrict__ part,
                                                uint* __restrict__ scal) {
    __shared__ float red[4];
    __shared__ float bc;
    {
        float m = part[threadIdx.x];  // MAXB == blockDim.x == 256
#pragma unroll
        for (int off = 32; off; off >>= 1) m = fmaxf(m, __shfl_xor(m, off, 64));
        if ((threadIdx.x & 63) == 0) red[threadIdx.x >> 6] = m;
        __syncthreads();
        if (blockIdx.x == 0)  // zero chunk max/arrival slots for the gemm
            for (int i = 1 + threadIdx.x; i < 8 + 2 * NT * NSLOT; i += 256)
                scal[i] = 0u;
        if (threadIdx.x == 0) {
            float r = fmaxf(fmaxf(red[0], red[1]), fmaxf(red[2], red[3]));
            bc = r;
            if (blockIdx.x == 0) scal[0] = __float_as_uint(r);
        }
        __syncthreads();
    }
    float s = bc / 127.0f;
    int stride = gridDim.x * blockDim.x;
    for (int i = blockIdx.x * blockDim.x + threadIdx.x; i < n8; i += stride) {
        f32x4 a = x[2 * i], b = x[2 * i + 1];
        uint r[8];
#pragma unroll
        for (int j = 0; j < 4; ++j) {
            float q0 = fminf(fmaxf(rintf(a[j] / s), -127.f), 127.f);
            float q1 = fminf(fmaxf(rintf(b[j] / s), -127.f), 127.f);
            r[j]     = __float_as_uint(q0) >> 16;  // exact: small ints fit bf16
            r[4 + j] = __float_as_uint(q1) >> 16;
        }
        uint4v o;
        o[0] = r[0] | (r[1] << 16); o[1] = r[2] | (r[3] << 16);
        o[2] = r[4] | (r[5] << 16); o[3] = r[6] | (r[7] << 16);
        xq[i] = o;
    }
}

// ---------------- SINGLE-PASS GEMM, immediate cross-block chunk-max -------
// BM=BN=128, BK=64, 256 threads (4 waves 2x2), 2-buffer LDS 64KB -> 2
// blocks/CU x 256 = all 512 blocks co-resident (bounds declared). Registers:
// only acc + acc_o (pass-2 budget, 108 VGPR proven) -- r16's third
// accumulator (the spill cause) is eliminated by waiting IMMEDIATELY after
// posting each chunk's max. The spin overlaps the in-flight prefetch of the
// next K-tiles (staged before the chunk tail). Deadlock-free: post(c)
// precedes wait(c) in every block. Replay-safe: quantx zeroes the slots
// each call. Max values and fp op order identical to two-pass -> bit-exact.
__global__ __launch_bounds__(256, 2) void k_gemm(const ushort* __restrict__ A,
                                                 const ushort* __restrict__ Bw,
                                                 uint* __restrict__ scal,
                                                 const float* __restrict__ bias,
                                                 float* __restrict__ out) {
    __shared__ ushort As[2][128 * 64];
    __shared__ ushort Bs[2][128 * 64];
    __shared__ float wmax2[4];
    __shared__ float bcast;

    const int tid = threadIdx.x;            // 0..255
    const int lane = tid & 63;
    const int wave = tid >> 6;              // 0..3
    const int wr = wave >> 1, wc = wave & 1;  // 2 x 2
    const int lr = lane & 15, half = lane >> 4;
    const int lx = lr & 7;

    // XCD-aware block mapping: each XCD gets an 8(bm) x 8(bn) cluster.
    const int bid = blockIdx.x;             // 0..511
    const int xcd = bid & 7, slot = bid >> 3;        // 8 XCDs x 64 slots
    const int bm = ((xcd & 1) << 3) | (slot & 7);    // 0..15
    const int bn = ((xcd >> 1) << 3) | (slot >> 3);  // 0..31
    const int brow = bm * 128, bcol = bn * 128;

    uint* maxsl = scal + 8;                 // [32][8]
    uint* cntsl = scal + 8 + NT * NSLOT;    // [32][8]
    const int xs = bid & 7;

    // staging: thread -> (row = tid>>3 [+inst*32], seg = tid&7), 16B each.
    const int srow = tid >> 3;              // 0..31
    const int sx8 = ((tid & 7) ^ (srow & 7)) * 8;
    const ushort* gA = A + (size_t)(brow + srow) * K + sx8;
    const ushort* gB = Bw + (size_t)(bcol + srow) * K + sx8;
    const int ldst = tid * 8;  // ushort offset of this thread's 16B slot

#define GLOAD(src, dst) \
    __builtin_amdgcn_global_load_lds((const GLOBAL_AS uint*)(src), (LDS_AS uint*)(dst), 16, 0, 0)

#define STAGE_ALL(buf, k0)                                                               \
    do {                                                                                 \
        _Pragma("unroll")                                                                \
        for (int inst = 0; inst < 4; ++inst)                                             \
            GLOAD(gA + (size_t)inst * 32 * K + (k0), &As[buf][inst * 2048 + ldst]);      \
        _Pragma("unroll")                                                                \
        for (int inst = 0; inst < 4; ++inst)                                             \
            GLOAD(gB + (size_t)inst * 32 * K + (k0), &Bs[buf][inst * 2048 + ldst]);      \
    } while (0)

    int rowA[4], rowB[4];
#pragma unroll
    for (int i = 0; i < 4; ++i) {
        rowA[i] = (wr * 64 + lr + i * 16) * 64;
        rowB[i] = (wc * 64 + lr + i * 16) * 64;
    }

    f32x4 acc[4][4], acc_o[4][4];
#pragma unroll
    for (int mi = 0; mi < 4; ++mi)
#pragma unroll
        for (int ni = 0; ni < 4; ++ni) {
            acc[mi][ni] = f32x4{0.f, 0.f, 0.f, 0.f};
            acc_o[mi][ni] = f32x4{0.f, 0.f, 0.f, 0.f};
        }

#define PHASE(buf, s2, STAGEL, TAIL)                                                     \
    do {                                                                                 \
        const int sx = (((s2) * 4 + half) ^ lx) * 8;                                     \
        short8 af[4], bf[4];                                                             \
        _Pragma("unroll")                                                                \
        for (int mi = 0; mi < 4; ++mi) af[mi] = *(const short8*)&As[buf][rowA[mi] + sx]; \
        _Pragma("unroll")                                                                \
        for (int ni = 0; ni < 4; ++ni) bf[ni] = *(const short8*)&Bs[buf][rowB[ni] + sx]; \
        STAGEL();                                                                        \
        __builtin_amdgcn_s_barrier();                                                    \
        asm volatile("s_waitcnt lgkmcnt(0)" ::: "memory");                               \
        __builtin_amdgcn_sched_barrier(0);                                               \
        __builtin_amdgcn_s_setprio(1);                                                   \
        _Pragma("unroll")                                                                \
        for (int mi = 0; mi < 4; ++mi)                                                   \
            _Pragma("unroll")                                                            \
            for (int ni = 0; ni < 4; ++ni)                                               \
                acc[mi][ni] = __builtin_amdgcn_mfma_f32_16x16x32_bf16(af[mi], bf[ni],    \
                                                                      acc[mi][ni], 0, 0, 0); \
        __builtin_amdgcn_s_setprio(0);                                                   \
        TAIL();                                                                          \
        __builtin_amdgcn_s_barrier();                                                    \
    } while (0)

    // prologue: stage tile 0 into buf 0.
    STAGE_ALL(0, 0);
    asm volatile("s_waitcnt vmcnt(0)" ::: "memory");
    __builtin_amdgcn_sched_barrier(0);
    __builtin_amdgcn_s_barrier();

    for (int t2 = 0; t2 < NKT; t2 += 2) {
        auto nop = [&]() {};
        auto stg1 = [&]() { STAGE_ALL(1, (t2 + 1) * 64); };
        auto stg2 = [&]() { if (t2 + 2 < NKT) STAGE_ALL(0, (t2 + 2) * 64); };
        auto tailA = [&]() {  // end of tile t2: buf1 must be landed
            asm volatile("s_waitcnt vmcnt(0)" ::: "memory");
            __builtin_amdgcn_sched_barrier(0);
        };
        // end of chunk t2/2: post block max -> device-wide wait -> quantize.
        // The spin overlaps the staged loads for tile t2+2 (issued above).
        auto tailB = [&]() {
            const int t = t2 >> 1;
            float m = 0.f;
#pragma unroll
            for (int mi = 0; mi < 4; ++mi)
#pragma unroll
                for (int ni = 0; ni < 4; ++ni) {
                    f32x4 v = acc[mi][ni];
                    m = fmaxf(m, fmaxf(fmaxf(fabsf(v[0]), fabsf(v[1])),
                                       fmaxf(fabsf(v[2]), fabsf(v[3]))));
                }
#pragma unroll
            for (int off = 32; off; off >>= 1) m = fmaxf(m, __shfl_xor(m, off, 64));
            if (lane == 0) wmax2[wave] = m;
            __syncthreads();
            if (tid == 0) {
                float bmv = fmaxf(fmaxf(wmax2[0], wmax2[1]), fmaxf(wmax2[2], wmax2[3]));
                atomicMax(&maxsl[t * NSLOT + xs], __float_as_uint(bmv));
                __threadfence();
                atomicAdd(&cntsl[t * NSLOT + xs], 1u);
                float gm = 0.f;
#pragma unroll
                for (int s = 0; s < NSLOT; ++s)
                    while (__hip_atomic_load(&cntsl[t * NSLOT + s], __ATOMIC_RELAXED,
                                             __HIP_MEMORY_SCOPE_AGENT) < NARRIVE) {}
                __threadfence();
#pragma unroll
                for (int s = 0; s < NSLOT; ++s)
                    gm = fmaxf(gm, __uint_as_float(__hip_atomic_load(
                                       &maxsl[t * NSLOT + s], __ATOMIC_RELAXED,
                                       __HIP_MEMORY_SCOPE_AGENT)));
                bcast = gm;
            }
            __syncthreads();
            float mt = bcast;
            float stp = mt / 127.0f;
            float inv = mt > 0.f ? 127.0f / mt : 0.f;
#pragma unroll
            for (int mi = 0; mi < 4; ++mi)
#pragma unroll
                for (int ni = 0; ni < 4; ++ni) {
#pragma unroll
                    for (int e = 0; e < 4; ++e)
                        acc_o[mi][ni][e] =
                            fmaf(rintf(acc[mi][ni][e] * inv), stp, acc_o[mi][ni][e]);
                    acc[mi][ni] = f32x4{0.f, 0.f, 0.f, 0.f};
                }
            if (t2 + 2 < NKT) {
                asm volatile("s_waitcnt vmcnt(0)" ::: "memory");
                __builtin_amdgcn_sched_barrier(0);
            }
        };

        // tile t2 (buf 0): stage all of tile t2+1 in phase 0
        PHASE(0, 0, stg1, nop);
        PHASE(0, 1, nop, tailA);
        // tile t2+1 (buf 1): stage all of tile t2+2 in phase 0
        PHASE(1, 0, stg2, nop);
        PHASE(1, 1, nop, tailB);
    }

    float sxq = __uint_as_float(scal[0]) / 127.0f;
#pragma unroll
    for (int mi = 0; mi < 4; ++mi)
#pragma unroll
        for (int ni = 0; ni < 4; ++ni) {
            int gr = brow + wr * 64 + mi * 16 + half * 4;
            int gc = bcol + wc * 64 + ni * 16 + lr;
            float bv = bias[gc];
#pragma unroll
            for (int e = 0; e < 4; ++e)
                out[(size_t)(gr + e) * OUT_ + gc] = fmaf(acc_o[mi][ni][e], sxq, bv);
        }
#undef PHASE
#undef STAGE_ALL
#undef GLOAD
}

extern "C" void kernel_launch(void* const* d_in, const int* in_sizes, int n_in,
                              void* d_out, int out_size, void* d_ws, size_t ws_size,
                              hipStream_t stream) {
    (void)in_sizes; (void)n_in; (void)out_size;
    const float* x   = (const float*)d_in[0];
    const float* W   = (const float*)d_in[1];
    const float* bias= (const float*)d_in[2];
    const float* dp  = (const float*)d_in[3];
    const float* dn  = (const float*)d_in[4];
    const float* npz = (const float*)d_in[5];
    const float* nnz = (const float*)d_in[6];
    float* out = (float*)d_out;

    uint* scal = (uint*)d_ws;
    ushort* xq = (ushort*)((char*)d_ws + 4096);
    ushort* wb = (ushort*)((char*)d_ws + 4096 + (size_t)B_ * IN_ * 2);
    float* part = (float*)((char*)d_ws + 4096 + (size_t)B_ * IN_ * 2 + (size_t)OUT_ * IN_ * 2);
    if (ws_size < 4096 + (size_t)B_ * IN_ * 2 + (size_t)OUT_ * IN_ * 2 + MAXB * 4) return;

    // fused maxabs partials (blocks 0..255) + weff one-shot NT (blocks 256..4351)
    k_prep<<<MAXB + OUT_ * IN_ / (256 * 16), 256, 0, stream>>>(
        (const f32x4*)x, B_ * IN_ / 4, part, (const f32x4*)W, (const f32x4*)dp,
        (const f32x4*)dn, (const f32x4*)npz, (const f32x4*)nnz, (uint2v*)wb);
    k_quantx<<<2048, 256, 0, stream>>>((const f32x4*)x, (uint4v*)xq, B_ * IN_ / 8,
                                       part, scal);
    k_gemm<<<512, 256, 0, stream>>>(xq, wb, scal, bias, out);
}

// Round 19
// 236.628 us; speedup vs baseline: 6.1941x; 6.1941x over previous
//
#include <hip/hip_runtime.h>
#include <stdint.h>

typedef unsigned int uint;
typedef unsigned short ushort;
typedef __attribute__((ext_vector_type(4))) float f32x4;
typedef __attribute__((ext_vector_type(8))) short short8;
typedef __attribute__((ext_vector_type(2))) uint uint2v;
typedef __attribute__((ext_vector_type(4))) uint uint4v;

#define GLOBAL_AS __attribute__((address_space(1)))
#define LDS_AS __attribute__((address_space(3)))

static constexpr int B_ = 2048, IN_ = 4096, OUT_ = 4096;
static constexpr int NT = 32;   // K chunks of 128 (crossbar tiles)
static constexpr int K = IN_;
static constexpr int NKT = 64;  // K-tiles of BK=64
static constexpr int MAXB = 256;   // maxabs partial blocks (fused into k_prep)

static constexpr double kGRangeD = 1e-4 - 1e-5;
static constexpr float kGMin  = 1e-5f;
static constexpr float kGMax  = 1e-4f;
static constexpr float kGRange = (float)kGRangeD;            // 9e-5
static constexpr float kD2D   = (float)(0.01 * kGRangeD);    // D2D_STD
static constexpr float kRead  = (float)(0.02 * kGRangeD);    // READ_NOISE_STD
static constexpr float kInvGR = (float)(1.0 / kGRangeD);     // decode scale

// ---------------- fused: maxabs partials (blocks < MAXB) + weff ------------
// maxabs: blocks 0..MAXB-1 -> per-block max|x| partials (no atomics).
// weff: one-shot, wave owns 4KB/stream, NONTEMPORAL loads (single-use
// streams bypass L3 -> no mutual eviction churn; r9/r12 A/B: NT ~18us faster).
__global__ __launch_bounds__(256) void k_prep(const f32x4* __restrict__ x, int n4,
                                              float* __restrict__ part,
                                              const f32x4* __restrict__ W,
                                              const f32x4* __restrict__ dp,
                                              const f32x4* __restrict__ dn,
                                              const f32x4* __restrict__ npz,
                                              const f32x4* __restrict__ nnz,
                                              uint2v* __restrict__ wb) {
    const int bid = blockIdx.x;
    const int tid = threadIdx.x;

    if (bid < MAXB) {
        __shared__ float wmax[4];
        int stride = MAXB * 256;
        float m = 0.f;
        for (int i = bid * 256 + tid; i < n4; i += stride) {
            f32x4 v = x[i];
            m = fmaxf(m, fmaxf(fmaxf(fabsf(v[0]), fabsf(v[1])),
                               fmaxf(fabsf(v[2]), fabsf(v[3]))));
        }
#pragma unroll
        for (int off = 32; off; off >>= 1) m = fmaxf(m, __shfl_xor(m, off, 64));
        if ((tid & 63) == 0) wmax[tid >> 6] = m;
        __syncthreads();
        if (tid == 0)
            part[bid] = fmaxf(fmaxf(wmax[0], wmax[1]), fmaxf(wmax[2], wmax[3]));
        return;
    }

    // ---- weff: one-shot 16 elems/thread, NT loads ----
    const int wid = ((bid - MAXB) * 256 + tid) >> 6;  // global wave id
    const int lane = tid & 63;
    const size_t base = (size_t)wid * 256 + lane;     // f32x4 index; +64 per j

    f32x4 w[4], a[4], b[4], c[4], d[4];
#pragma unroll
    for (int j = 0; j < 4; ++j) {
        w[j] = __builtin_nontemporal_load(&W[base + j * 64]);
        a[j] = __builtin_nontemporal_load(&dp[base + j * 64]);
        b[j] = __builtin_nontemporal_load(&dn[base + j * 64]);
        c[j] = __builtin_nontemporal_load(&npz[base + j * 64]);
        d[j] = __builtin_nontemporal_load(&nnz[base + j * 64]);
    }
#pragma unroll
    for (int j = 0; j < 4; ++j) {
        uint h[4];
#pragma unroll
        for (int e = 0; e < 4; ++e) {
            float wc = fminf(fmaxf(w[j][e], -1.f), 1.f);
            float gp = kGMin + fmaxf(wc, 0.f) * kGRange;
            float gn = kGMin + fmaxf(-wc, 0.f) * kGRange;
            gp = fminf(fmaxf(gp + kD2D * a[j][e] + kRead * c[j][e], 0.f), kGMax);
            gn = fminf(fmaxf(gn + kD2D * b[j][e] + kRead * d[j][e], 0.f), kGMax);
            float wv = (gp - gn) * kInvGR;
            uint u = __float_as_uint(wv);
            h[e] = (u + 0x7FFFu + ((u >> 16) & 1u)) >> 16;  // RNE to bf16
        }
        uint2v o;
        o[0] = h[0] | (h[1] << 16); o[1] = h[2] | (h[3] << 16);
        wb[base + j * 64] = o;
    }
}

// ---------------- DAC quantize x (folds partial-max reduce + scal init) ---
// Each block reduces the MAXB partials itself (order-independent -> identical
// scale bits). Block 0 publishes scal[0] and zeroes scal[1..NT] for gemm1.
__global__ __launch_bounds__(256) void k_quantx(const f32x4* __restrict__ x,
                                                uint4v* __restrict__ xq, int n8,
                                                const float* __restrict__ part,
                                                uint* __restrict__ scal) {
    __shared__ float red[4];
    __shared__ float bc;
    {
        float m = part[threadIdx.x];  // MAXB == blockDim.x == 256
#pragma unroll
        for (int off = 32; off; off >>= 1) m = fmaxf(m, __shfl_xor(m, off, 64));
        if ((threadIdx.x & 63) == 0) red[threadIdx.x >> 6] = m;
        __syncthreads();
        if (blockIdx.x == 0 && threadIdx.x >= 1 && threadIdx.x <= NT)
            scal[threadIdx.x] = 0u;  // chunk-max slots for gemm pass 1
        if (threadIdx.x == 0) {
            float r = fmaxf(fmaxf(red[0], red[1]), fmaxf(red[2], red[3]));
            bc = r;
            if (blockIdx.x == 0) scal[0] = __float_as_uint(r);
        }
        __syncthreads();
    }
    float s = bc / 127.0f;
    int stride = gridDim.x * blockDim.x;
    for (int i = blockIdx.x * blockDim.x + threadIdx.x; i < n8; i += stride) {
        f32x4 a = x[2 * i], b = x[2 * i + 1];
        uint r[8];
#pragma unroll
        for (int j = 0; j < 4; ++j) {
            float q0 = fminf(fmaxf(rintf(a[j] / s), -127.f), 127.f);
            float q1 = fminf(fmaxf(rintf(b[j] / s), -127.f), 127.f);
            r[j]     = __float_as_uint(q0) >> 16;  // exact: small ints fit bf16
            r[4 + j] = __float_as_uint(q1) >> 16;
        }
        uint4v o;
        o[0] = r[0] | (r[1] << 16); o[1] = r[2] | (r[3] << 16);
        o[2] = r[4] | (r[5] << 16); o[3] = r[6] | (r[7] << 16);
        xq[i] = o;
    }
}

// ---------------- two-pass phase-interleaved GEMM with per-chunk ADC ------
// BM=BN=128, BK=64, 256 threads (4 waves, 2Mx2N), per-wave 64x64 out.
// 2-buffer LDS (64KB -> 2 blocks/CU for cross-block latency hiding, m114).
template <int PASS>
__global__ __launch_bounds__(256, 2) void k_gemm(const ushort* __restrict__ A,
                                                 const ushort* __restrict__ Bw,
                                                 uint* __restrict__ scal,
                                                 const float* __restrict__ bias,
                                                 float* __restrict__ out) {
    __shared__ ushort As[2][128 * 64];
    __shared__ ushort Bs[2][128 * 64];
    __shared__ uint cmax[NT];

    const int tid = threadIdx.x;            // 0..255
    const int lane = tid & 63;
    const int wave = tid >> 6;              // 0..3
    const int wr = wave >> 1, wc = wave & 1;  // 2 x 2
    const int lr = lane & 15, half = lane >> 4;
    const int lx = lr & 7;

    // XCD-aware block mapping: each XCD gets an 8(bm) x 8(bn) cluster.
    const int bid = blockIdx.x;             // 0..511
    const int xcd = bid & 7, slot = bid >> 3;        // 8 XCDs x 64 slots
    const int bm = ((xcd & 1) << 3) | (slot & 7);    // 0..15
    const int bn = ((xcd >> 1) << 3) | (slot >> 3);  // 0..31
    const int brow = bm * 128, bcol = bn * 128;

    if (PASS == 1 && tid < NT) cmax[tid] = 0u;

    // staging: thread -> (row = tid>>3 [+inst*32], seg = tid&7), 16B each.
    const int srow = tid >> 3;              // 0..31
    const int sx8 = ((tid & 7) ^ (srow & 7)) * 8;
    const ushort* gA = A + (size_t)(brow + srow) * K + sx8;
    const ushort* gB = Bw + (size_t)(bcol + srow) * K + sx8;
    const int ldst = tid * 8;  // ushort offset of this thread's 16B slot

#define GLOAD(src, dst) \
    __builtin_amdgcn_global_load_lds((const GLOBAL_AS uint*)(src), (LDS_AS uint*)(dst), 16, 0, 0)

    // full tile stage: 4 instrs A (32 rows each) + 4 instrs B.
#define STAGE_ALL(buf, k0)                                                               \
    do {                                                                                 \
        _Pragma("unroll")                                                                \
        for (int inst = 0; inst < 4; ++inst)                                             \
            GLOAD(gA + (size_t)inst * 32 * K + (k0), &As[buf][inst * 2048 + ldst]);      \
        _Pragma("unroll")                                                                \
        for (int inst = 0; inst < 4; ++inst)                                             \
            GLOAD(gB + (size_t)inst * 32 * K + (k0), &Bs[buf][inst * 2048 + ldst]);      \
    } while (0)

    // fragment row offsets (ushort units, ld=64)
    int rowA[4], rowB[4];
#pragma unroll
    for (int i = 0; i < 4; ++i) {
        rowA[i] = (wr * 64 + lr + i * 16) * 64;
        rowB[i] = (wc * 64 + lr + i * 16) * 64;
    }

    f32x4 acc[4][4], acc_o[4][4];
#pragma unroll
    for (int mi = 0; mi < 4; ++mi)
#pragma unroll
        for (int ni = 0; ni < 4; ++ni) {
            acc[mi][ni] = f32x4{0.f, 0.f, 0.f, 0.f};
            acc_o[mi][ni] = f32x4{0.f, 0.f, 0.f, 0.f};
        }

    // one phase; STAGEL/TAIL are named lambdas (so #pragma stays legal).
#define PHASE(buf, s2, STAGEL, TAIL)                                                     \
    do {                                                                                 \
        const int sx = (((s2) * 4 + half) ^ lx) * 8;                                     \
        short8 af[4], bf[4];                                                             \
        _Pragma("unroll")                                                                \
        for (int mi = 0; mi < 4; ++mi) af[mi] = *(const short8*)&As[buf][rowA[mi] + sx]; \
        _Pragma("unroll")                                                                \
        for (int ni = 0; ni < 4; ++ni) bf[ni] = *(const short8*)&Bs[buf][rowB[ni] + sx]; \
        STAGEL();                                                                        \
        __builtin_amdgcn_s_barrier();                                                    \
        asm volatile("s_waitcnt lgkmcnt(0)" ::: "memory");                               \
        __builtin_amdgcn_sched_barrier(0);                                               \
        __builtin_amdgcn_s_setprio(1);                                                   \
        _Pragma("unroll")                                                                \
        for (int mi = 0; mi < 4; ++mi)                                                   \
            _Pragma("unroll")                                                            \
            for (int ni = 0; ni < 4; ++ni)                                               \
                acc[mi][ni] = __builtin_amdgcn_mfma_f32_16x16x32_bf16(af[mi], bf[ni],    \
                                                                      acc[mi][ni], 0, 0, 0); \
        __builtin_amdgcn_s_setprio(0);                                                   \
        TAIL();                                                                          \
        __builtin_amdgcn_s_barrier();                                                    \
    } while (0)

    // prologue: stage tile 0 into buf 0.
    STAGE_ALL(0, 0);
    asm volatile("s_waitcnt vmcnt(0)" ::: "memory");
    __builtin_amdgcn_sched_barrier(0);
    __builtin_amdgcn_s_barrier();

    for (int t2 = 0; t2 < NKT; t2 += 2) {
        auto nop = [&]() {};
        auto stg1 = [&]() { STAGE_ALL(1, (t2 + 1) * 64); };
        auto stg2 = [&]() { if (t2 + 2 < NKT) STAGE_ALL(0, (t2 + 2) * 64); };
        auto tailA = [&]() {  // end of tile t2: buf1 must be landed
            asm volatile("s_waitcnt vmcnt(0)" ::: "memory");
            __builtin_amdgcn_sched_barrier(0);
        };
        auto tailB = [&]() {  // end of tile t2+1: ADC for chunk t2/2, then drain
            const int t = t2 >> 1;
            if (PASS == 1) {
                float m = 0.f;
#pragma unroll
                for (int mi = 0; mi < 4; ++mi)
#pragma unroll
                    for (int ni = 0; ni < 4; ++ni) {
                        f32x4 v = acc[mi][ni];
                        m = fmaxf(m, fmaxf(fmaxf(fabsf(v[0]), fabsf(v[1])),
                                           fmaxf(fabsf(v[2]), fabsf(v[3]))));
                    }
#pragma unroll
                for (int off = 32; off; off >>= 1) m = fmaxf(m, __shfl_xor(m, off, 64));
                if (lane == 0) atomicMax(&cmax[t], __float_as_uint(m));
            } else {
                float mt = __uint_as_float(scal[1 + t]);
                float stp = mt / 127.0f;
                float inv = mt > 0.f ? 127.0f / mt : 0.f;
#pragma unroll
                for (int mi = 0; mi < 4; ++mi)
#pragma unroll
                    for (int ni = 0; ni < 4; ++ni)
#pragma unroll
                        for (int e = 0; e < 4; ++e)
                            acc_o[mi][ni][e] =
                                fmaf(rintf(acc[mi][ni][e] * inv), stp, acc_o[mi][ni][e]);
            }
#pragma unroll
            for (int mi = 0; mi < 4; ++mi)
#pragma unroll
                for (int ni = 0; ni < 4; ++ni) acc[mi][ni] = f32x4{0.f, 0.f, 0.f, 0.f};
            if (t2 + 2 < NKT) {
                asm volatile("s_waitcnt vmcnt(0)" ::: "memory");
                __builtin_amdgcn_sched_barrier(0);
            }
        };

        // tile t2 (buf 0): stage all of tile t2+1 in phase 0
        PHASE(0, 0, stg1, nop);
        PHASE(0, 1, nop, tailA);
        // tile t2+1 (buf 1): stage all of tile t2+2 in phase 0
        PHASE(1, 0, stg2, nop);
        PHASE(1, 1, nop, tailB);
    }

    if (PASS == 1) {
        __syncthreads();
        if (tid < NT) atomicMax(&scal[1 + tid], cmax[tid]);
    } else {
        float sxq = __uint_as_float(scal[0]) / 127.0f;
#pragma unroll
        for (int mi = 0; mi < 4; ++mi)
#pragma unroll
            for (int ni = 0; ni < 4; ++ni) {
                int gr = brow + wr * 64 + mi * 16 + half * 4;
                int gc = bcol + wc * 64 + ni * 16 + lr;
                float bv = bias[gc];
#pragma unroll
                for (int e = 0; e < 4; ++e)
                    out[(size_t)(gr + e) * OUT_ + gc] = fmaf(acc_o[mi][ni][e], sxq, bv);
            }
    }
#undef PHASE
#undef STAGE_ALL
#undef GLOAD
}

extern "C" void kernel_launch(void* const* d_in, const int* in_sizes, int n_in,
                              void* d_out, int out_size, void* d_ws, size_t ws_size,
                              hipStream_t stream) {
    (void)in_sizes; (void)n_in; (void)out_size;
    const float* x   = (const float*)d_in[0];
    const float* W   = (const float*)d_in[1];
    const float* bias= (const float*)d_in[2];
    const float* dp  = (const float*)d_in[3];
    const float* dn  = (const float*)d_in[4];
    const float* npz = (const float*)d_in[5];
    const float* nnz = (const float*)d_in[6];
    float* out = (float*)d_out;

    uint* scal = (uint*)d_ws;
    ushort* xq = (ushort*)((char*)d_ws + 256);
    ushort* wb = (ushort*)((char*)d_ws + 256 + (size_t)B_ * IN_ * 2);
    float* part = (float*)((char*)d_ws + 256 + (size_t)B_ * IN_ * 2 + (size_t)OUT_ * IN_ * 2);
    if (ws_size < 256 + (size_t)B_ * IN_ * 2 + (size_t)OUT_ * IN_ * 2 + MAXB * 4) return;

    // fused maxabs partials (blocks 0..255) + weff one-shot NT (blocks 256..4351)
    k_prep<<<MAXB + OUT_ * IN_ / (256 * 16), 256, 0, stream>>>(
        (const f32x4*)x, B_ * IN_ / 4, part, (const f32x4*)W, (const f32x4*)dp,
        (const f32x4*)dn, (const f32x4*)npz, (const f32x4*)nnz, (uint2v*)wb);
    k_quantx<<<2048, 256, 0, stream>>>((const f32x4*)x, (uint4v*)xq, B_ * IN_ / 8,
                                       part, scal);
    k_gemm<1><<<512, 256, 0, stream>>>(xq, wb, scal, bias, out);
    k_gemm<2><<<512, 256, 0, stream>>>(xq, wb, scal, bias, out);
}